// Round 1
// baseline (3452.843 us; speedup 1.0000x reference)
//
#include <hip/hip_runtime.h>
#include <math.h>

// Problem constants
#define NN 8192
#define INS 512
#define FEAT 128

// ws layout (float offsets)
#define WS_XW 0
#define WS_XT 4194304
#define WS_Q  8388608
#define WS_K  9437184
#define WS_PP 10485760
#define WS_PQ 10518528
#define WS_AD 10551296
#define WS_QT 10551808
// total 10552320 floats = 42.2 MB

// ---------------------------------------------------------------------------
// K1: xw = x @ weight, xt = x @ weight_time   ([8192,512] @ [512,512])
// 64x64 tile, BK=16, 256 threads, 4x4 micro-tile, fp32.
// ---------------------------------------------------------------------------
__global__ __launch_bounds__(256) void gemm_xw(const float* __restrict__ x,
                                               const float* __restrict__ wA,
                                               const float* __restrict__ wB,
                                               float* __restrict__ xw,
                                               float* __restrict__ xt) {
    const float* w = (blockIdx.z == 0) ? wA : wB;
    float* outp    = (blockIdx.z == 0) ? xw : xt;
    __shared__ float As[16][68];   // [k][m], pad 68 keeps float4 alignment
    __shared__ float Bs[16][68];   // [k][n]
    const int t = threadIdx.x;
    const int m0 = blockIdx.y * 64, n0 = blockIdx.x * 64;
    const int tn = t & 15, tm = t >> 4;
    float acc[4][4] = {};
    for (int k0 = 0; k0 < 512; k0 += 16) {
        {   // A tile: x[m0+m][k0+k] -> As[k][m]
            int m = t >> 2, k4 = (t & 3) * 4;
            float4 a4 = *(const float4*)&x[(m0 + m) * 512 + k0 + k4];
            As[k4 + 0][m] = a4.x; As[k4 + 1][m] = a4.y;
            As[k4 + 2][m] = a4.z; As[k4 + 3][m] = a4.w;
        }
        {   // B tile: w[k0+k][n0+n] -> Bs[k][n]
            int k = t >> 4, n4 = (t & 15) * 4;
            *(float4*)&Bs[k][n4] = *(const float4*)&w[(k0 + k) * 512 + n0 + n4];
        }
        __syncthreads();
        #pragma unroll
        for (int k = 0; k < 16; ++k) {
            float4 a = *(float4*)&As[k][tm * 4];
            float4 b = *(float4*)&Bs[k][tn * 4];
            float aa[4] = {a.x, a.y, a.z, a.w};
            float bb[4] = {b.x, b.y, b.z, b.w};
            #pragma unroll
            for (int i = 0; i < 4; ++i)
                #pragma unroll
                for (int j = 0; j < 4; ++j)
                    acc[i][j] += aa[i] * bb[j];
        }
        __syncthreads();
    }
    #pragma unroll
    for (int i = 0; i < 4; ++i) {
        float4 v = make_float4(acc[i][0], acc[i][1], acc[i][2], acc[i][3]);
        *(float4*)&outp[(m0 + tm * 4 + i) * 512 + n0 + tn * 4] = v;
    }
}

// ---------------------------------------------------------------------------
// K2: q = x @ W0^T, k = x @ W1^T   ([8192,512] @ [512,128]^T)
// Block handles 8 rows of x; thread t<128 -> q feature t, t>=128 -> k feature.
// ---------------------------------------------------------------------------
__global__ __launch_bounds__(256) void qk_kernel(const float* __restrict__ x,
                                                 const float* __restrict__ W0,
                                                 const float* __restrict__ W1,
                                                 float* __restrict__ q,
                                                 float* __restrict__ k) {
    __shared__ float Xs[8][512];
    const int t = threadIdx.x;
    const int i0 = blockIdx.x * 8;
    #pragma unroll
    for (int it = 0; it < 4; ++it) {
        int idx = it * 256 + t;            // 1024 float4s = 8x512
        int r = idx >> 7, c4 = (idx & 127) * 4;
        *(float4*)&Xs[r][c4] = *(const float4*)&x[(i0 + r) * 512 + c4];
    }
    __syncthreads();
    const float* wrow = (t < 128) ? &W0[t * 512] : &W1[(t - 128) * 512];
    float acc[8] = {};
    for (int kk = 0; kk < 512; kk += 4) {
        float4 w4 = *(const float4*)&wrow[kk];
        #pragma unroll
        for (int rr = 0; rr < 8; ++rr) {
            float4 x4 = *(float4*)&Xs[rr][kk];
            acc[rr] += w4.x * x4.x + w4.y * x4.y + w4.z * x4.z + w4.w * x4.w;
        }
    }
    float* dst = (t < 128) ? &q[t] : &k[t - 128];
    #pragma unroll
    for (int rr = 0; rr < 8; ++rr) dst[(i0 + rr) * 128] = acc[rr];
}

// ---------------------------------------------------------------------------
// K3: time part.  T = G_time @ xt via prefix sums; writes out = 0.5*T.
//   T[i,d] = (n*A_d - B_{i,d}) / S_i,  B = 2i*P_i - 2Q_i + Qtot - i*A_d
// ---------------------------------------------------------------------------
__global__ __launch_bounds__(256) void time_part1(const float* __restrict__ xt,
                                                  float* __restrict__ pP,
                                                  float* __restrict__ pQ) {
    int d = blockIdx.x * 256 + threadIdx.x;
    int r0 = blockIdx.y * 128;
    float sp = 0.f, sq = 0.f;
    for (int r = 0; r < 128; ++r) {
        float v = xt[(r0 + r) * 512 + d];
        sp += v;
        sq += (float)(r0 + r) * v;
    }
    pP[blockIdx.y * 512 + d] = sp;
    pQ[blockIdx.y * 512 + d] = sq;
}

__global__ __launch_bounds__(512) void time_part2(float* __restrict__ pP,
                                                  float* __restrict__ pQ,
                                                  float* __restrict__ Ad,
                                                  float* __restrict__ Qt) {
    int d = threadIdx.x;                 // 512 cols, one block
    float rp = 0.f, rq = 0.f;
    for (int c = 0; c < 64; ++c) {
        int idx = c * 512 + d;
        float p = pP[idx], qv = pQ[idx];
        pP[idx] = rp; pQ[idx] = rq;      // exclusive prefix
        rp += p; rq += qv;
    }
    Ad[d] = rp; Qt[d] = rq;
}

__global__ __launch_bounds__(256) void time_part3(const float* __restrict__ xt,
                                                  const float* __restrict__ pP,
                                                  const float* __restrict__ pQ,
                                                  const float* __restrict__ Ad,
                                                  const float* __restrict__ Qt,
                                                  float* __restrict__ out) {
    int d = blockIdx.x * 256 + threadIdx.x;
    int r0 = blockIdx.y * 128;
    float P = pP[blockIdx.y * 512 + d];
    float Q = pQ[blockIdx.y * 512 + d];
    float A = Ad[d], Qtot = Qt[d];
    for (int r = 0; r < 128; ++r) {
        int i = r0 + r;
        float v = xt[i * 512 + d];
        P += v;
        float fi = (float)i;
        Q += fi * v;
        float B = 2.f * fi * P - 2.f * Q + Qtot - fi * A;
        // exact integer row sum of the band matrix
        int Si = 67108864 - (i * (i + 1)) / 2 - ((8191 - i) * (8192 - i)) / 2;
        float T = (8192.f * A - B) / (float)Si;
        out[i * 512 + d] = 0.5f * T;
    }
}

// ---------------------------------------------------------------------------
// K4: flash attention, fp32.  O = softmax(q k^T) @ xw ; out += 0.5 * O / l
// BM=32 rows/block, BN=32 K-rows/tile, 256 threads, V staged transposed in
// 4 phases of 128 cols (keeps static LDS < 64 KB). Stride-34 padding gives
// 2-way-max LDS bank aliasing on the hot float2 reads (free per m136).
// ---------------------------------------------------------------------------
__global__ __launch_bounds__(256) void flash_attn(const float* __restrict__ q,
                                                  const float* __restrict__ kmat,
                                                  const float* __restrict__ v,
                                                  float* __restrict__ out) {
    __shared__ float Qs[32 * 130];
    __shared__ float Ks[32 * 130];
    __shared__ float Vt[128 * 34];       // transposed V phase: [c_local][j]
    __shared__ float Ps[32 * 34];
    __shared__ float red[32 * 8];
    __shared__ float mrow[32], lrow[32], arow[32];

    const int t = threadIdx.x;
    const int i0 = blockIdx.x * 32;

    // stage Q tile (persistent for whole block)
    #pragma unroll
    for (int it = 0; it < 4; ++it) {
        int idx = it * 256 + t;          // 1024 float4s = 32x128
        int r = idx >> 5, k4 = (idx & 31) * 4;
        float4 q4 = *(const float4*)&q[(i0 + r) * 128 + k4];
        Qs[r * 130 + k4 + 0] = q4.x; Qs[r * 130 + k4 + 1] = q4.y;
        Qs[r * 130 + k4 + 2] = q4.z; Qs[r * 130 + k4 + 3] = q4.w;
    }
    if (t < 32) { mrow[t] = -INFINITY; lrow[t] = 0.f; }

    const int rS = t & 31, cg = t >> 5;          // S-phase mapping
    const int r0 = (t >> 5) * 4, cl = t & 31;    // PV mapping: 4 rows x 16 cols
    float o[4][16];
    #pragma unroll
    for (int a = 0; a < 4; ++a)
        #pragma unroll
        for (int b = 0; b < 16; ++b) o[a][b] = 0.f;

    for (int j0 = 0; j0 < NN; j0 += 32) {
        __syncthreads();                 // previous tile fully consumed
        #pragma unroll
        for (int it = 0; it < 4; ++it) { // stage K tile
            int idx = it * 256 + t;
            int r = idx >> 5, k4 = (idx & 31) * 4;
            float4 kv = *(const float4*)&kmat[(j0 + r) * 128 + k4];
            Ks[r * 130 + k4 + 0] = kv.x; Ks[r * 130 + k4 + 1] = kv.y;
            Ks[r * 130 + k4 + 2] = kv.z; Ks[r * 130 + k4 + 3] = kv.w;
        }
        __syncthreads();

        // S = Q K^T : thread computes row rS, cols cg*4..+3
        float s[4] = {0.f, 0.f, 0.f, 0.f};
        const float* qp = &Qs[rS * 130];
        #pragma unroll 8
        for (int kk = 0; kk < 128; kk += 2) {
            float2 q2 = *(float2*)&qp[kk];
            #pragma unroll
            for (int cc = 0; cc < 4; ++cc) {
                float2 k2 = *(float2*)&Ks[(cg * 4 + cc) * 130 + kk];
                s[cc] += q2.x * k2.x + q2.y * k2.y;
            }
        }

        // online softmax
        float tmx = fmaxf(fmaxf(s[0], s[1]), fmaxf(s[2], s[3]));
        red[rS * 8 + cg] = tmx;
        __syncthreads();
        if (t < 32) {
            float m8 = red[t * 8];
            #pragma unroll
            for (int u = 1; u < 8; ++u) m8 = fmaxf(m8, red[t * 8 + u]);
            float mo = mrow[t];
            float mn = fmaxf(mo, m8);
            mrow[t] = mn;
            arow[t] = __expf(mo - mn);   // 0 on first tile (mo = -inf)
        }
        __syncthreads();
        float mn = mrow[rS];
        float psum = 0.f;
        #pragma unroll
        for (int cc = 0; cc < 4; ++cc) {
            float p = __expf(s[cc] - mn);
            Ps[rS * 34 + cg * 4 + cc] = p;
            psum += p;
        }
        red[rS * 8 + cg] = psum;
        __syncthreads();
        if (t < 32) {
            float sum = 0.f;
            #pragma unroll
            for (int u = 0; u < 8; ++u) sum += red[t * 8 + u];
            lrow[t] = lrow[t] * arow[t] + sum;
        }

        // rescale accumulators by alpha
        #pragma unroll
        for (int rr = 0; rr < 4; ++rr) {
            float al = arow[r0 + rr];
            #pragma unroll
            for (int cc = 0; cc < 16; ++cc) o[rr][cc] *= al;
        }

        // PV in 4 column-phases of 128
        #pragma unroll
        for (int ph = 0; ph < 4; ++ph) {
            __syncthreads();
            #pragma unroll
            for (int it = 0; it < 4; ++it) {   // stage V cols [ph*128, +128)
                int idx = it * 256 + t;        // 1024 float4s = 32x128
                int j = idx >> 5, c4 = (idx & 31) * 4;
                float4 v4 = *(const float4*)&v[(j0 + j) * 512 + ph * 128 + c4];
                Vt[(c4 + 0) * 34 + j] = v4.x; Vt[(c4 + 1) * 34 + j] = v4.y;
                Vt[(c4 + 2) * 34 + j] = v4.z; Vt[(c4 + 3) * 34 + j] = v4.w;
            }
            __syncthreads();
            #pragma unroll 4
            for (int j2 = 0; j2 < 16; ++j2) {
                int j = j2 * 2;
                float2 p2[4];
                #pragma unroll
                for (int rr = 0; rr < 4; ++rr)
                    p2[rr] = *(float2*)&Ps[(r0 + rr) * 34 + j];
                #pragma unroll
                for (int cc4 = 0; cc4 < 4; ++cc4) {
                    float2 v2 = *(float2*)&Vt[(cl + 32 * cc4) * 34 + j];
                    int cc = ph * 4 + cc4;
                    #pragma unroll
                    for (int rr = 0; rr < 4; ++rr)
                        o[rr][cc] += p2[rr].x * v2.x + p2[rr].y * v2.y;
                }
            }
        }
    }
    __syncthreads();
    #pragma unroll
    for (int rr = 0; rr < 4; ++rr) {
        float li = 0.5f / lrow[r0 + rr];
        int row = i0 + r0 + rr;
        #pragma unroll
        for (int cc = 0; cc < 16; ++cc)
            out[row * 512 + cl + 32 * cc] += li * o[rr][cc];
    }
}

// ---------------------------------------------------------------------------
extern "C" void kernel_launch(void* const* d_in, const int* in_sizes, int n_in,
                              void* d_out, int out_size, void* d_ws, size_t ws_size,
                              hipStream_t stream) {
    const float* x  = (const float*)d_in[0];
    const float* W0 = (const float*)d_in[1];
    const float* W1 = (const float*)d_in[2];
    const float* w  = (const float*)d_in[3];
    const float* wt = (const float*)d_in[4];
    float* out = (float*)d_out;
    float* ws  = (float*)d_ws;
    float* xw = ws + WS_XW;
    float* xt = ws + WS_XT;
    float* q  = ws + WS_Q;
    float* k  = ws + WS_K;
    float* pP = ws + WS_PP;
    float* pQ = ws + WS_PQ;
    float* Ad = ws + WS_AD;
    float* Qt = ws + WS_QT;

    gemm_xw   <<<dim3(8, 128, 2), 256, 0, stream>>>(x, w, wt, xw, xt);
    qk_kernel <<<dim3(1024),      256, 0, stream>>>(x, W0, W1, q, k);
    time_part1<<<dim3(2, 64),     256, 0, stream>>>(xt, pP, pQ);
    time_part2<<<dim3(1),         512, 0, stream>>>(pP, pQ, Ad, Qt);
    time_part3<<<dim3(2, 64),     256, 0, stream>>>(xt, pP, pQ, Ad, Qt, out);
    flash_attn<<<dim3(256),       256, 0, stream>>>(q, k, xw, out);
}

// Round 2
// 851.505 us; speedup vs baseline: 4.0550x; 4.0550x over previous
//
#include <hip/hip_runtime.h>
#include <math.h>

// Problem constants
#define NN 8192
#define INS 512
#define FEAT 128

typedef unsigned short ush;
typedef short bf16x8 __attribute__((ext_vector_type(8)));
typedef float f32x4 __attribute__((ext_vector_type(4)));

__device__ __forceinline__ ush f2bf(float f) {           // RNE fp32->bf16
    unsigned u = __float_as_uint(f);
    unsigned r = (u + 0x7FFFu + ((u >> 16) & 1u)) >> 16;
    return (ush)r;
}
__device__ __forceinline__ float bf2f(ush h) {
    return __uint_as_float(((unsigned)h) << 16);
}

// ws layout (float offsets). Regions are time-multiplexed:
//  [WS_XW..)  xw fp32 (gemm) -> after transpose: partial0/partial1 bf16 (pass2)
//  [WS_XT..)  xt fp32 (time path) -> after time_part3: VtG bf16 + Mrow + Rl
#define WS_XW 0
#define WS_XT 4194304
#define WS_M  6291456
#define WS_RL 6299648
#define WS_QH 8388608
#define WS_QL 8912896
#define WS_KH 9437184
#define WS_KL 9961472
#define WS_PP 10485760
#define WS_PQ 10518528
#define WS_AD 10551296
#define WS_QT 10551808
// total 10552320 floats = 42.2 MB (same as round 1)

// ---------------------------------------------------------------------------
// K1: xw = x @ weight, xt = x @ weight_time  (fp32, unchanged from R1)
// ---------------------------------------------------------------------------
__global__ __launch_bounds__(256) void gemm_xw(const float* __restrict__ x,
                                               const float* __restrict__ wA,
                                               const float* __restrict__ wB,
                                               float* __restrict__ xw,
                                               float* __restrict__ xt) {
    const float* w = (blockIdx.z == 0) ? wA : wB;
    float* outp    = (blockIdx.z == 0) ? xw : xt;
    __shared__ float As[16][68];
    __shared__ float Bs[16][68];
    const int t = threadIdx.x;
    const int m0 = blockIdx.y * 64, n0 = blockIdx.x * 64;
    const int tn = t & 15, tm = t >> 4;
    float acc[4][4] = {};
    for (int k0 = 0; k0 < 512; k0 += 16) {
        {
            int m = t >> 2, k4 = (t & 3) * 4;
            float4 a4 = *(const float4*)&x[(m0 + m) * 512 + k0 + k4];
            As[k4 + 0][m] = a4.x; As[k4 + 1][m] = a4.y;
            As[k4 + 2][m] = a4.z; As[k4 + 3][m] = a4.w;
        }
        {
            int k = t >> 4, n4 = (t & 15) * 4;
            *(float4*)&Bs[k][n4] = *(const float4*)&w[(k0 + k) * 512 + n0 + n4];
        }
        __syncthreads();
        #pragma unroll
        for (int k = 0; k < 16; ++k) {
            float4 a = *(float4*)&As[k][tm * 4];
            float4 b = *(float4*)&Bs[k][tn * 4];
            float aa[4] = {a.x, a.y, a.z, a.w};
            float bb[4] = {b.x, b.y, b.z, b.w};
            #pragma unroll
            for (int i = 0; i < 4; ++i)
                #pragma unroll
                for (int j = 0; j < 4; ++j)
                    acc[i][j] += aa[i] * bb[j];
        }
        __syncthreads();
    }
    #pragma unroll
    for (int i = 0; i < 4; ++i) {
        float4 v = make_float4(acc[i][0], acc[i][1], acc[i][2], acc[i][3]);
        *(float4*)&outp[(m0 + tm * 4 + i) * 512 + n0 + tn * 4] = v;
    }
}

// ---------------------------------------------------------------------------
// K2: q/k projections -> bf16 hi/lo arrays qh,ql,kh,kl [8192][128]
// ---------------------------------------------------------------------------
__global__ __launch_bounds__(256) void qk_kernel(const float* __restrict__ x,
                                                 const float* __restrict__ W0,
                                                 const float* __restrict__ W1,
                                                 ush* __restrict__ qh, ush* __restrict__ ql,
                                                 ush* __restrict__ kh, ush* __restrict__ kl) {
    __shared__ float Xs[8][512];
    const int t = threadIdx.x;
    const int i0 = blockIdx.x * 8;
    #pragma unroll
    for (int it = 0; it < 4; ++it) {
        int idx = it * 256 + t;
        int r = idx >> 7, c4 = (idx & 127) * 4;
        *(float4*)&Xs[r][c4] = *(const float4*)&x[(i0 + r) * 512 + c4];
    }
    __syncthreads();
    const float* wrow = (t < 128) ? &W0[t * 512] : &W1[(t - 128) * 512];
    float acc[8] = {};
    for (int kk = 0; kk < 512; kk += 4) {
        float4 w4 = *(const float4*)&wrow[kk];
        #pragma unroll
        for (int rr = 0; rr < 8; ++rr) {
            float4 x4 = *(float4*)&Xs[rr][kk];
            acc[rr] += w4.x * x4.x + w4.y * x4.y + w4.z * x4.z + w4.w * x4.w;
        }
    }
    ush* dh = (t < 128) ? &qh[t] : &kh[t - 128];
    ush* dl = (t < 128) ? &ql[t] : &kl[t - 128];
    #pragma unroll
    for (int rr = 0; rr < 8; ++rr) {
        float v = acc[rr];
        ush h = f2bf(v);
        float lo = v - bf2f(h);
        dh[(i0 + rr) * 128] = h;
        dl[(i0 + rr) * 128] = f2bf(lo);
    }
}

// ---------------------------------------------------------------------------
// K3: time path (unchanged from R1). time_part3 writes out = 0.5*T.
// ---------------------------------------------------------------------------
__global__ __launch_bounds__(256) void time_part1(const float* __restrict__ xt,
                                                  float* __restrict__ pP,
                                                  float* __restrict__ pQ) {
    int d = blockIdx.x * 256 + threadIdx.x;
    int r0 = blockIdx.y * 128;
    float sp = 0.f, sq = 0.f;
    for (int r = 0; r < 128; ++r) {
        float v = xt[(r0 + r) * 512 + d];
        sp += v;
        sq += (float)(r0 + r) * v;
    }
    pP[blockIdx.y * 512 + d] = sp;
    pQ[blockIdx.y * 512 + d] = sq;
}

__global__ __launch_bounds__(512) void time_part2(float* __restrict__ pP,
                                                  float* __restrict__ pQ,
                                                  float* __restrict__ Ad,
                                                  float* __restrict__ Qt) {
    int d = threadIdx.x;
    float rp = 0.f, rq = 0.f;
    for (int c = 0; c < 64; ++c) {
        int idx = c * 512 + d;
        float p = pP[idx], qv = pQ[idx];
        pP[idx] = rp; pQ[idx] = rq;
        rp += p; rq += qv;
    }
    Ad[d] = rp; Qt[d] = rq;
}

__global__ __launch_bounds__(256) void time_part3(const float* __restrict__ xt,
                                                  const float* __restrict__ pP,
                                                  const float* __restrict__ pQ,
                                                  const float* __restrict__ Ad,
                                                  const float* __restrict__ Qt,
                                                  float* __restrict__ out) {
    int d = blockIdx.x * 256 + threadIdx.x;
    int r0 = blockIdx.y * 128;
    float P = pP[blockIdx.y * 512 + d];
    float Q = pQ[blockIdx.y * 512 + d];
    float A = Ad[d], Qtot = Qt[d];
    for (int r = 0; r < 128; ++r) {
        int i = r0 + r;
        float v = xt[i * 512 + d];
        P += v;
        float fi = (float)i;
        Q += fi * v;
        float B = 2.f * fi * P - 2.f * Q + Qtot - fi * A;
        int Si = 67108864 - (i * (i + 1)) / 2 - ((8191 - i) * (8192 - i)) / 2;
        float T = (8192.f * A - B) / (float)Si;
        out[i * 512 + d] = 0.5f * T;
    }
}

// ---------------------------------------------------------------------------
// K4: transpose xw fp32 [8192][512] -> VtG bf16 [512][8192]
// ---------------------------------------------------------------------------
__global__ __launch_bounds__(256) void transpose_v(const float* __restrict__ xw,
                                                   ush* __restrict__ vt) {
    __shared__ float T[64][65];
    const int t = threadIdx.x;
    const int c0 = blockIdx.x * 64;   // xw col / Vt row base
    const int i0 = blockIdx.y * 64;   // xw row / Vt col base
    #pragma unroll
    for (int u = 0; u < 4; ++u) {
        int idx = u * 256 + t;
        int r = idx >> 4, c4 = (idx & 15) * 4;
        *(float4*)&T[r][c4] = *(const float4*)&xw[(i0 + r) * 512 + c0 + c4];
    }
    __syncthreads();
    #pragma unroll
    for (int u = 0; u < 4; ++u) {
        int idx = u * 256 + t;
        int a = idx >> 4, b4 = (idx & 15) * 4;   // a: Vt row-local, b4: Vt col-local
        ush h0 = f2bf(T[b4 + 0][a]);
        ush h1 = f2bf(T[b4 + 1][a]);
        ush h2 = f2bf(T[b4 + 2][a]);
        ush h3 = f2bf(T[b4 + 3][a]);
        uint2 pk;
        pk.x = (unsigned)h0 | ((unsigned)h1 << 16);
        pk.y = (unsigned)h2 | ((unsigned)h3 << 16);
        *(uint2*)&vt[(c0 + a) * 8192 + i0 + b4] = pk;
    }
}

// ---------------------------------------------------------------------------
// K5: pass1 — softmax stats. M_i = max_j s_ij, Rl_i = 1/sum_j exp(s-M).
// grid 256 (32 Q-rows/block), 4 waves: wave w -> rowtile (w&1), coltile (w>>1).
// Per-wave running (m,l) over its 16-col slice held in registers; merged once.
// ---------------------------------------------------------------------------
__global__ __launch_bounds__(256) void pass1(const ush* __restrict__ qhg,
                                             const ush* __restrict__ qlg,
                                             const ush* __restrict__ khg,
                                             const ush* __restrict__ klg,
                                             float* __restrict__ Mrow,
                                             float* __restrict__ Rl) {
    __shared__ __align__(16) ush Kh[32 * 128];
    __shared__ __align__(16) ush Kl[32 * 128];
    __shared__ float sm[2][32], sl[2][32];
    const int t = threadIdx.x;
    const int lane = t & 63, w = t >> 6;
    const int rt = w & 1, ct = w >> 1;
    const int i0 = blockIdx.x * 32;
    const int l15 = lane & 15, g = lane >> 4;

    // Q fragments (A operand), rows 16*rt .. +15
    bf16x8 Qh[4], Ql[4];
    {
        int qrow = i0 + rt * 16 + l15;
        #pragma unroll
        for (int kt = 0; kt < 4; ++kt) {
            Qh[kt] = *(const bf16x8*)&qhg[qrow * 128 + kt * 32 + g * 8];
            Ql[kt] = *(const bf16x8*)&qlg[qrow * 128 + kt * 32 + g * 8];
        }
    }
    float m_run[4] = {-INFINITY, -INFINITY, -INFINITY, -INFINITY};
    float l_run[4] = {0.f, 0.f, 0.f, 0.f};

    for (int j0 = 0; j0 < NN; j0 += 32) {
        __syncthreads();
        #pragma unroll
        for (int u = 0; u < 2; ++u) {   // stage K tile, swizzled granules
            int s = u * 256 + t;
            int n = s >> 4, gl = (s & 15) ^ (n & 15);
            int src = (j0 + n) * 128 + gl * 8;
            *(uint4*)&Kh[s * 8] = *(const uint4*)&khg[src];
            *(uint4*)&Kl[s * 8] = *(const uint4*)&klg[src];
        }
        __syncthreads();

        bf16x8 kbh[4], kbl[4];
        {
            int n = ct * 16 + l15;
            #pragma unroll
            for (int kt = 0; kt < 4; ++kt) {
                int slot = n * 16 + ((kt * 4 + g) ^ (n & 15));
                kbh[kt] = *(const bf16x8*)&Kh[slot * 8];
                kbl[kt] = *(const bf16x8*)&Kl[slot * 8];
            }
        }
        f32x4 s4 = {0.f, 0.f, 0.f, 0.f};
        #pragma unroll
        for (int kt = 0; kt < 4; ++kt) s4 = __builtin_amdgcn_mfma_f32_16x16x32_bf16(Qh[kt], kbh[kt], s4, 0, 0, 0);
        #pragma unroll
        for (int kt = 0; kt < 4; ++kt) s4 = __builtin_amdgcn_mfma_f32_16x16x32_bf16(Ql[kt], kbh[kt], s4, 0, 0, 0);
        #pragma unroll
        for (int kt = 0; kt < 4; ++kt) s4 = __builtin_amdgcn_mfma_f32_16x16x32_bf16(Qh[kt], kbl[kt], s4, 0, 0, 0);

        #pragma unroll
        for (int reg = 0; reg < 4; ++reg) {
            float s = s4[reg];
            float mx = s;
            mx = fmaxf(mx, __shfl_xor(mx, 1));
            mx = fmaxf(mx, __shfl_xor(mx, 2));
            mx = fmaxf(mx, __shfl_xor(mx, 4));
            mx = fmaxf(mx, __shfl_xor(mx, 8));
            float mn = fmaxf(m_run[reg], mx);
            float p = __expf(s - mn);
            p += __shfl_xor(p, 1);
            p += __shfl_xor(p, 2);
            p += __shfl_xor(p, 4);
            p += __shfl_xor(p, 8);
            l_run[reg] = l_run[reg] * __expf(m_run[reg] - mn) + p;
            m_run[reg] = mn;
        }
    }
    if (l15 == 0) {
        #pragma unroll
        for (int reg = 0; reg < 4; ++reg) {
            sm[ct][rt * 16 + g * 4 + reg] = m_run[reg];
            sl[ct][rt * 16 + g * 4 + reg] = l_run[reg];
        }
    }
    __syncthreads();
    if (t < 32) {
        float M = fmaxf(sm[0][t], sm[1][t]);
        float l = sl[0][t] * __expf(sm[0][t] - M) + sl[1][t] * __expf(sm[1][t] - M);
        Mrow[i0 + t] = M;
        Rl[i0 + t] = 1.0f / l;
    }
}

// ---------------------------------------------------------------------------
// K6: pass2 — O_partial = exp(S-M)/l @ V for one key-half, via transposed PV:
// O^T(512x64) = Vt_tile(512x32) * P^T(32x64). grid (2 jhalves, 128 strips).
// BM=64 Q rows, BN=32 keys/iter. Wave w: S rows 32(w&1)+{0..31}, cols 16(w>>1);
// PV vcols 128w..+127. 3 barriers/iter, no cross-wave softmax.
// ---------------------------------------------------------------------------
__global__ __launch_bounds__(256, 1) void pass2(const ush* __restrict__ qhg,
                                                const ush* __restrict__ qlg,
                                                const ush* __restrict__ khg,
                                                const ush* __restrict__ klg,
                                                const ush* __restrict__ vtg,
                                                const float* __restrict__ Mrow,
                                                const float* __restrict__ Rl,
                                                ush* __restrict__ part0,
                                                ush* __restrict__ part1) {
    __shared__ __align__(16) ush Kh[32 * 128];   // 8 KB, granule-swizzled
    __shared__ __align__(16) ush Kl[32 * 128];   // 8 KB
    __shared__ __align__(16) ush Vt[512 * 32];   // 32 KB, granule-swizzled
    __shared__ __align__(16) ush P[64 * 40];     // 5 KB, row stride 40 ush = 80 B

    const int t = threadIdx.x;
    const int lane = t & 63, w = t >> 6;
    const int l15 = lane & 15, g = lane >> 4;
    const int i0 = blockIdx.y * 64;
    const int jbase = blockIdx.x * 4096;

    // Q fragments: 2 rowtiles (rows 32*(w&1) + rt*16 + l15)
    bf16x8 Qh[2][4], Ql[2][4];
    #pragma unroll
    for (int rt = 0; rt < 2; ++rt) {
        int qrow = i0 + 32 * (w & 1) + rt * 16 + l15;
        #pragma unroll
        for (int kt = 0; kt < 4; ++kt) {
            Qh[rt][kt] = *(const bf16x8*)&qhg[qrow * 128 + kt * 32 + g * 8];
            Ql[rt][kt] = *(const bf16x8*)&qlg[qrow * 128 + kt * 32 + g * 8];
        }
    }
    // Per-row softmax constants for this lane's C-layout rows
    float Mv[2][4], Rv[2][4];
    #pragma unroll
    for (int rt = 0; rt < 2; ++rt)
        #pragma unroll
        for (int reg = 0; reg < 4; ++reg) {
            int row = i0 + 32 * (w & 1) + rt * 16 + g * 4 + reg;
            Mv[rt][reg] = Mrow[row];
            Rv[rt][reg] = Rl[row];
        }

    f32x4 acc[8][4];
    #pragma unroll
    for (int mt = 0; mt < 8; ++mt)
        #pragma unroll
        for (int nt = 0; nt < 4; ++nt)
            acc[mt][nt] = (f32x4){0.f, 0.f, 0.f, 0.f};

    for (int jt = 0; jt < 128; ++jt) {
        const int j0 = jbase + jt * 32;
        __syncthreads();                       // prev iter LDS fully consumed
        #pragma unroll
        for (int u = 0; u < 2; ++u) {          // stage K hi/lo
            int s = u * 256 + t;
            int n = s >> 4, gl = (s & 15) ^ (n & 15);
            int src = (j0 + n) * 128 + gl * 8;
            *(uint4*)&Kh[s * 8] = *(const uint4*)&khg[src];
            *(uint4*)&Kl[s * 8] = *(const uint4*)&klg[src];
        }
        #pragma unroll
        for (int u = 0; u < 8; ++u) {          // stage Vt (cols j0..j0+31)
            int s = u * 256 + t;
            int c = s >> 2, gl = (s & 3) ^ ((c >> 1) & 3);
            *(uint4*)&Vt[s * 8] = *(const uint4*)&vtg[c * 8192 + j0 + gl * 8];
        }
        __syncthreads();                       // staged

        // ---- S = Q K^T (B-fragments from swizzled K tiles) ----
        bf16x8 kbh[4], kbl[4];
        {
            int n = (w >> 1) * 16 + l15;
            #pragma unroll
            for (int kt = 0; kt < 4; ++kt) {
                int slot = n * 16 + ((kt * 4 + g) ^ (n & 15));
                kbh[kt] = *(const bf16x8*)&Kh[slot * 8];
                kbl[kt] = *(const bf16x8*)&Kl[slot * 8];
            }
        }
        #pragma unroll
        for (int rt = 0; rt < 2; ++rt) {
            f32x4 s4 = {0.f, 0.f, 0.f, 0.f};
            #pragma unroll
            for (int kt = 0; kt < 4; ++kt) s4 = __builtin_amdgcn_mfma_f32_16x16x32_bf16(Qh[rt][kt], kbh[kt], s4, 0, 0, 0);
            #pragma unroll
            for (int kt = 0; kt < 4; ++kt) s4 = __builtin_amdgcn_mfma_f32_16x16x32_bf16(Ql[rt][kt], kbh[kt], s4, 0, 0, 0);
            #pragma unroll
            for (int kt = 0; kt < 4; ++kt) s4 = __builtin_amdgcn_mfma_f32_16x16x32_bf16(Qh[rt][kt], kbl[kt], s4, 0, 0, 0);
            #pragma unroll
            for (int reg = 0; reg < 4; ++reg) {
                float p = __expf(s4[reg] - Mv[rt][reg]) * Rv[rt][reg];
                int row = 32 * (w & 1) + rt * 16 + g * 4 + reg;
                int col = (w >> 1) * 16 + l15;
                P[row * 40 + col] = f2bf(p);
            }
        }
        __syncthreads();                       // P visible to all waves

        // ---- O^T += Vt_tile * P^T ----
        bf16x8 Pb[4];
        #pragma unroll
        for (int nt = 0; nt < 4; ++nt)
            Pb[nt] = *(const bf16x8*)&P[(nt * 16 + l15) * 40 + g * 8];
        #pragma unroll
        for (int mt = 0; mt < 8; ++mt) {
            int c = w * 128 + mt * 16 + l15;
            int slot = c * 4 + (g ^ ((c >> 1) & 3));
            bf16x8 vf = *(const bf16x8*)&Vt[slot * 8];
            #pragma unroll
            for (int nt = 0; nt < 4; ++nt)
                acc[mt][nt] = __builtin_amdgcn_mfma_f32_16x16x32_bf16(vf, Pb[nt], acc[mt][nt], 0, 0, 0);
        }
    }

    // Epilogue: write bf16 partial [qrow][vcol]
    ush* prt = (blockIdx.x == 0) ? part0 : part1;
    #pragma unroll
    for (int mt = 0; mt < 8; ++mt)
        #pragma unroll
        for (int nt = 0; nt < 4; ++nt) {
            int qrow = i0 + nt * 16 + l15;
            int vcol = w * 128 + mt * 16 + g * 4;
            ush h0 = f2bf(acc[mt][nt][0]);
            ush h1 = f2bf(acc[mt][nt][1]);
            ush h2 = f2bf(acc[mt][nt][2]);
            ush h3 = f2bf(acc[mt][nt][3]);
            uint2 pk;
            pk.x = (unsigned)h0 | ((unsigned)h1 << 16);
            pk.y = (unsigned)h2 | ((unsigned)h3 << 16);
            *(uint2*)&prt[qrow * 512 + vcol] = pk;
        }
}

// ---------------------------------------------------------------------------
// K7: merge — out += 0.5 * (part0 + part1)
// ---------------------------------------------------------------------------
__global__ __launch_bounds__(256) void merge_k(const ush* __restrict__ p0,
                                               const ush* __restrict__ p1,
                                               float* __restrict__ out) {
    int base = (blockIdx.x * 256 + threadIdx.x) * 8;
    uint4 a = *(const uint4*)&p0[base];
    uint4 b = *(const uint4*)&p1[base];
    float4 o0 = *(float4*)&out[base];
    float4 o1 = *(float4*)&out[base + 4];
    unsigned av[4] = {a.x, a.y, a.z, a.w};
    unsigned bv[4] = {b.x, b.y, b.z, b.w};
    float r[8];
    #pragma unroll
    for (int i = 0; i < 4; ++i) {
        r[2 * i + 0] = 0.5f * (bf2f((ush)(av[i] & 0xFFFF)) + bf2f((ush)(bv[i] & 0xFFFF)));
        r[2 * i + 1] = 0.5f * (bf2f((ush)(av[i] >> 16)) + bf2f((ush)(bv[i] >> 16)));
    }
    o0.x += r[0]; o0.y += r[1]; o0.z += r[2]; o0.w += r[3];
    o1.x += r[4]; o1.y += r[5]; o1.z += r[6]; o1.w += r[7];
    *(float4*)&out[base] = o0;
    *(float4*)&out[base + 4] = o1;
}

// ---------------------------------------------------------------------------
extern "C" void kernel_launch(void* const* d_in, const int* in_sizes, int n_in,
                              void* d_out, int out_size, void* d_ws, size_t ws_size,
                              hipStream_t stream) {
    const float* x  = (const float*)d_in[0];
    const float* W0 = (const float*)d_in[1];
    const float* W1 = (const float*)d_in[2];
    const float* wm = (const float*)d_in[3];
    const float* wt = (const float*)d_in[4];
    float* out = (float*)d_out;
    float* ws  = (float*)d_ws;

    float* xw = ws + WS_XW;
    float* xt = ws + WS_XT;
    ush*   vtg = (ush*)(ws + WS_XT);        // overlays xt after time_part3
    float* Mr = ws + WS_M;
    float* Rl = ws + WS_RL;
    ush* qh = (ush*)(ws + WS_QH);
    ush* ql = (ush*)(ws + WS_QL);
    ush* kh = (ush*)(ws + WS_KH);
    ush* kl = (ush*)(ws + WS_KL);
    float* pP = ws + WS_PP;
    float* pQ = ws + WS_PQ;
    float* Ad = ws + WS_AD;
    float* Qt = ws + WS_QT;
    ush* part0 = (ush*)(ws + WS_XW);        // overlays xw after transpose
    ush* part1 = (ush*)(ws + WS_XW + 2097152);

    gemm_xw    <<<dim3(8, 128, 2), 256, 0, stream>>>(x, wm, wt, xw, xt);
    qk_kernel  <<<dim3(1024),      256, 0, stream>>>(x, W0, W1, qh, ql, kh, kl);
    time_part1 <<<dim3(2, 64),     256, 0, stream>>>(xt, pP, pQ);
    time_part2 <<<dim3(1),         512, 0, stream>>>(pP, pQ, Ad, Qt);
    time_part3 <<<dim3(2, 64),     256, 0, stream>>>(xt, pP, pQ, Ad, Qt, out);
    transpose_v<<<dim3(8, 128),    256, 0, stream>>>(xw, vtg);
    pass1      <<<dim3(256),       256, 0, stream>>>(qh, ql, kh, kl, Mr, Rl);
    pass2      <<<dim3(2, 128),    256, 0, stream>>>(qh, ql, kh, kl, vtg, Mr, Rl, part0, part1);
    merge_k    <<<dim3(2048),      256, 0, stream>>>(part0, part1, out);
}

// Round 4
// 583.224 us; speedup vs baseline: 5.9203x; 1.4600x over previous
//
#include <hip/hip_runtime.h>
#include <math.h>

// Problem constants
#define NN 8192
#define INS 512
#define FEAT 128

typedef unsigned short ush;
typedef short bf16x8 __attribute__((ext_vector_type(8)));
typedef float f32x4 __attribute__((ext_vector_type(4)));

__device__ __forceinline__ ush f2bf(float f) {           // RNE fp32->bf16
    unsigned u = __float_as_uint(f);
    unsigned r = (u + 0x7FFFu + ((u >> 16) & 1u)) >> 16;
    return (ush)r;
}
__device__ __forceinline__ float bf2f(ush h) {
    return __uint_as_float(((unsigned)h) << 16);
}
// trunc-split 8 floats into hi bf16 (truncation) + lo bf16 (RNE of residual).
__device__ __forceinline__ void split8(float4 f0, float4 f1, uint4& h, uint4& l) {
    float f[8] = {f0.x, f0.y, f0.z, f0.w, f1.x, f1.y, f1.z, f1.w};
    unsigned hu[8], lu[8];
    #pragma unroll
    for (int j = 0; j < 8; ++j) {
        unsigned u = __float_as_uint(f[j]);
        hu[j] = u >> 16;
        float lo = f[j] - __uint_as_float(u & 0xFFFF0000u);
        lu[j] = (unsigned)f2bf(lo);
    }
    h.x = hu[0] | (hu[1] << 16); h.y = hu[2] | (hu[3] << 16);
    h.z = hu[4] | (hu[5] << 16); h.w = hu[6] | (hu[7] << 16);
    l.x = lu[0] | (lu[1] << 16); l.y = lu[2] | (lu[3] << 16);
    l.z = lu[4] | (lu[5] << 16); l.w = lu[6] | (lu[7] << 16);
}

// ws layout (float offsets), total = 10,552,320 floats = 42.2 MB.
//  A [0,2097152)        : vtg bf16 [512][8192]
//  B [2097152,4194304)  : xt bf16 -> (after time path) Mrow/Rl/pm/pl
//  C [4194304,8388608)  : weights hi/lo (early) -> part0/part1 bf16 (pass2)
//      W01h 4194304+65536 | W01l 4259840+65536 | wmTh 4325376+131072
//      wmTl 4456448+131072 | wtTh 4587520+131072 | wtTl 4718592+131072 (end 4849664)
//      part0 4194304+2097152 | part1 6291456+2097152   (weights dead by pass2)
//  D [8388608,10485760) : qh,ql,kh,kl bf16 [8192][128]
//  E [10485760,10552320): pP,pQ,Ad,Qt fp32

// ---------------------------------------------------------------------------
// cast_w01: W0,W1 [128][512] fp32 -> W01h/W01l [256][512] bf16
// ---------------------------------------------------------------------------
__global__ __launch_bounds__(256) void cast_w01(const float* __restrict__ W0,
                                                const float* __restrict__ W1,
                                                ush* __restrict__ W01h,
                                                ush* __restrict__ W01l) {
    int idx = (blockIdx.x * 256 + threadIdx.x) * 8;      // 131072 elements total
    int r = idx >> 9, c = idx & 511;
    const float* src = (r < 128) ? &W0[r * 512 + c] : &W1[(r - 128) * 512 + c];
    float4 f0 = *(const float4*)src;
    float4 f1 = *(const float4*)(src + 4);
    uint4 h, l;
    split8(f0, f1, h, l);
    *(uint4*)&W01h[idx] = h;
    *(uint4*)&W01l[idx] = l;
}

// ---------------------------------------------------------------------------
// cast_wT: wm/wt [512k][512n] fp32 -> transposed hi/lo bf16 [512n][512k]
// ---------------------------------------------------------------------------
__global__ __launch_bounds__(256) void cast_wT(const float* __restrict__ wm,
                                               const float* __restrict__ wt,
                                               ush* __restrict__ wmTh, ush* __restrict__ wmTl,
                                               ush* __restrict__ wtTh, ush* __restrict__ wtTl) {
    const float* src = blockIdx.z ? wt : wm;
    ush* oh = blockIdx.z ? wtTh : wmTh;
    ush* ol = blockIdx.z ? wtTl : wmTl;
    __shared__ float T[64][65];
    const int t = threadIdx.x;
    const int k0 = blockIdx.y * 64, n0 = blockIdx.x * 64;
    #pragma unroll
    for (int u = 0; u < 4; ++u) {
        int idx = u * 256 + t;
        int r = idx >> 4, c4 = (idx & 15) * 4;
        *(float4*)&T[r][c4] = *(const float4*)&src[(k0 + r) * 512 + n0 + c4];
    }
    __syncthreads();
    #pragma unroll
    for (int u = 0; u < 4; ++u) {
        int idx = u * 256 + t;
        int a = idx >> 4, b4 = (idx & 15) * 4;   // out row n0+a, k cols k0+b4..+3
        unsigned hu[4], lu[4];
        #pragma unroll
        for (int j = 0; j < 4; ++j) {
            float f = T[b4 + j][a];
            unsigned uu = __float_as_uint(f);
            hu[j] = uu >> 16;
            lu[j] = (unsigned)f2bf(f - __uint_as_float(uu & 0xFFFF0000u));
        }
        uint2 hp, lp;
        hp.x = hu[0] | (hu[1] << 16); hp.y = hu[2] | (hu[3] << 16);
        lp.x = lu[0] | (lu[1] << 16); lp.y = lu[2] | (lu[3] << 16);
        *(uint2*)&oh[(n0 + a) * 512 + k0 + b4] = hp;
        *(uint2*)&ol[(n0 + a) * 512 + k0 + b4] = lp;
    }
}

// ---------------------------------------------------------------------------
// gemm_xv: C = x @ w (hi/lo bf16 MFMA, 3 terms), 128x128 tile, BK=32.
// z=0: w=weight, writes vtg TRANSPOSED (bf16). z=1: w=weight_time, writes xt.
// ---------------------------------------------------------------------------
__global__ __launch_bounds__(256) void gemm_xv(const float* __restrict__ x,
    const ush* __restrict__ wmTh, const ush* __restrict__ wmTl,
    const ush* __restrict__ wtTh, const ush* __restrict__ wtTl,
    ush* __restrict__ vtg, ush* __restrict__ xtb) {
    const bool isV = (blockIdx.z == 0);
    const ush* Bhg = isV ? wmTh : wtTh;
    const ush* Blg = isV ? wmTl : wtTl;
    __shared__ __align__(16) ush sm[20480];   // 40 KB; reused as LT in epilogue
    ush* Ah = sm;
    ush* Al = sm + 5120;
    ush* Bh = sm + 10240;
    ush* Bl = sm + 15360;
    const int t = threadIdx.x;
    const int lane = t & 63, w = t >> 6;
    const int l15 = lane & 15, g4 = lane >> 4;
    const int m0 = blockIdx.y * 128, n0 = blockIdx.x * 128;
    const int wm0 = (w & 1) * 64, wn0 = (w >> 1) * 64;
    f32x4 acc[4][4];
    #pragma unroll
    for (int mt = 0; mt < 4; ++mt)
        #pragma unroll
        for (int nt = 0; nt < 4; ++nt)
            acc[mt][nt] = (f32x4){0.f, 0.f, 0.f, 0.f};

    const int am = t >> 1, akh = (t & 1) * 16;
    for (int k0 = 0; k0 < 512; k0 += 32) {
        __syncthreads();
        {   // stage A (x fp32 -> hi/lo bf16 granules)
            const float* src = &x[(m0 + am) * 512 + k0 + akh];
            float4 f0 = *(const float4*)&src[0];
            float4 f1 = *(const float4*)&src[4];
            float4 f2 = *(const float4*)&src[8];
            float4 f3 = *(const float4*)&src[12];
            uint4 h0, l0, h1, l1;
            split8(f0, f1, h0, l0);
            split8(f2, f3, h1, l1);
            int s0 = am * 5 + (akh >> 3);
            *(uint4*)&Ah[s0 * 8] = h0; *(uint4*)&Ah[(s0 + 1) * 8] = h1;
            *(uint4*)&Al[s0 * 8] = l0; *(uint4*)&Al[(s0 + 1) * 8] = l1;
        }
        #pragma unroll
        for (int u = 0; u < 2; ++u) {   // stage B (pre-split bf16)
            int s = u * 256 + t;
            int n = s >> 2, g = s & 3;
            int srco = (n0 + n) * 512 + k0 + g * 8;
            int slot = n * 5 + g;
            *(uint4*)&Bh[slot * 8] = *(const uint4*)&Bhg[srco];
            *(uint4*)&Bl[slot * 8] = *(const uint4*)&Blg[srco];
        }
        __syncthreads();
        bf16x8 ah[4], al[4], bh[4], bl[4];
        #pragma unroll
        for (int mt = 0; mt < 4; ++mt) {
            int slot = (wm0 + mt * 16 + l15) * 5 + g4;
            ah[mt] = *(const bf16x8*)&Ah[slot * 8];
            al[mt] = *(const bf16x8*)&Al[slot * 8];
        }
        #pragma unroll
        for (int nt = 0; nt < 4; ++nt) {
            int slot = (wn0 + nt * 16 + l15) * 5 + g4;
            bh[nt] = *(const bf16x8*)&Bh[slot * 8];
            bl[nt] = *(const bf16x8*)&Bl[slot * 8];
        }
        #pragma unroll
        for (int mt = 0; mt < 4; ++mt)
            #pragma unroll
            for (int nt = 0; nt < 4; ++nt) {
                acc[mt][nt] = __builtin_amdgcn_mfma_f32_16x16x32_bf16(ah[mt], bh[nt], acc[mt][nt], 0, 0, 0);
                acc[mt][nt] = __builtin_amdgcn_mfma_f32_16x16x32_bf16(al[mt], bh[nt], acc[mt][nt], 0, 0, 0);
                acc[mt][nt] = __builtin_amdgcn_mfma_f32_16x16x32_bf16(ah[mt], bl[nt], acc[mt][nt], 0, 0, 0);
            }
    }

    if (!isV) {   // xt: direct bf16 stores
        #pragma unroll
        for (int mt = 0; mt < 4; ++mt)
            #pragma unroll
            for (int nt = 0; nt < 4; ++nt) {
                int col = n0 + wn0 + nt * 16 + l15;
                int rowb = m0 + wm0 + mt * 16 + g4 * 4;
                #pragma unroll
                for (int reg = 0; reg < 4; ++reg)
                    xtb[(rowb + reg) * 512 + col] = f2bf(acc[mt][nt][reg]);
            }
    } else {      // vtg: transpose through LDS
        __syncthreads();
        #pragma unroll
        for (int mt = 0; mt < 4; ++mt)
            #pragma unroll
            for (int nt = 0; nt < 4; ++nt) {
                int nl = wn0 + nt * 16 + l15;
                int mb = wm0 + mt * 16 + g4 * 4;
                uint2 pk;
                pk.x = (unsigned)f2bf(acc[mt][nt][0]) | ((unsigned)f2bf(acc[mt][nt][1]) << 16);
                pk.y = (unsigned)f2bf(acc[mt][nt][2]) | ((unsigned)f2bf(acc[mt][nt][3]) << 16);
                *(uint2*)&sm[nl * 136 + mb] = pk;
            }
        __syncthreads();
        int a = t >> 1, off = (t & 1) * 64;
        #pragma unroll
        for (int u = 0; u < 8; ++u)
            *(uint4*)&vtg[(n0 + a) * 8192 + m0 + off + u * 8] =
                *(const uint4*)&sm[a * 136 + off + u * 8];
    }
}

// ---------------------------------------------------------------------------
// gemm_qk: [q|k] = x @ [W0|W1]^T (hi/lo MFMA) -> qh/ql/kh/kl
// ---------------------------------------------------------------------------
__global__ __launch_bounds__(256) void gemm_qk(const float* __restrict__ x,
    const ush* __restrict__ W01h, const ush* __restrict__ W01l,
    ush* __restrict__ qh, ush* __restrict__ ql,
    ush* __restrict__ kh, ush* __restrict__ kl) {
    __shared__ __align__(16) ush sm[20480];
    ush* Ah = sm;
    ush* Al = sm + 5120;
    ush* Bh = sm + 10240;
    ush* Bl = sm + 15360;
    const int t = threadIdx.x;
    const int lane = t & 63, w = t >> 6;
    const int l15 = lane & 15, g4 = lane >> 4;
    const int m0 = blockIdx.y * 128, n0 = blockIdx.x * 128;
    const int wm0 = (w & 1) * 64, wn0 = (w >> 1) * 64;
    f32x4 acc[4][4];
    #pragma unroll
    for (int mt = 0; mt < 4; ++mt)
        #pragma unroll
        for (int nt = 0; nt < 4; ++nt)
            acc[mt][nt] = (f32x4){0.f, 0.f, 0.f, 0.f};

    const int am = t >> 1, akh = (t & 1) * 16;
    for (int k0 = 0; k0 < 512; k0 += 32) {
        __syncthreads();
        {
            const float* src = &x[(m0 + am) * 512 + k0 + akh];
            float4 f0 = *(const float4*)&src[0];
            float4 f1 = *(const float4*)&src[4];
            float4 f2 = *(const float4*)&src[8];
            float4 f3 = *(const float4*)&src[12];
            uint4 h0, l0, h1, l1;
            split8(f0, f1, h0, l0);
            split8(f2, f3, h1, l1);
            int s0 = am * 5 + (akh >> 3);
            *(uint4*)&Ah[s0 * 8] = h0; *(uint4*)&Ah[(s0 + 1) * 8] = h1;
            *(uint4*)&Al[s0 * 8] = l0; *(uint4*)&Al[(s0 + 1) * 8] = l1;
        }
        #pragma unroll
        for (int u = 0; u < 2; ++u) {
            int s = u * 256 + t;
            int n = s >> 2, g = s & 3;
            int srco = (n0 + n) * 512 + k0 + g * 8;
            int slot = n * 5 + g;
            *(uint4*)&Bh[slot * 8] = *(const uint4*)&W01h[srco];
            *(uint4*)&Bl[slot * 8] = *(const uint4*)&W01l[srco];
        }
        __syncthreads();
        bf16x8 ah[4], al[4], bh[4], bl[4];
        #pragma unroll
        for (int mt = 0; mt < 4; ++mt) {
            int slot = (wm0 + mt * 16 + l15) * 5 + g4;
            ah[mt] = *(const bf16x8*)&Ah[slot * 8];
            al[mt] = *(const bf16x8*)&Al[slot * 8];
        }
        #pragma unroll
        for (int nt = 0; nt < 4; ++nt) {
            int slot = (wn0 + nt * 16 + l15) * 5 + g4;
            bh[nt] = *(const bf16x8*)&Bh[slot * 8];
            bl[nt] = *(const bf16x8*)&Bl[slot * 8];
        }
        #pragma unroll
        for (int mt = 0; mt < 4; ++mt)
            #pragma unroll
            for (int nt = 0; nt < 4; ++nt) {
                acc[mt][nt] = __builtin_amdgcn_mfma_f32_16x16x32_bf16(ah[mt], bh[nt], acc[mt][nt], 0, 0, 0);
                acc[mt][nt] = __builtin_amdgcn_mfma_f32_16x16x32_bf16(al[mt], bh[nt], acc[mt][nt], 0, 0, 0);
                acc[mt][nt] = __builtin_amdgcn_mfma_f32_16x16x32_bf16(ah[mt], bl[nt], acc[mt][nt], 0, 0, 0);
            }
    }
    ush* oh = (n0 == 0) ? qh : kh;
    ush* ol = (n0 == 0) ? ql : kl;
    #pragma unroll
    for (int mt = 0; mt < 4; ++mt)
        #pragma unroll
        for (int nt = 0; nt < 4; ++nt) {
            int col = (wn0 + nt * 16 + l15) & 127;
            int rowb = m0 + wm0 + mt * 16 + g4 * 4;
            #pragma unroll
            for (int reg = 0; reg < 4; ++reg) {
                float v = acc[mt][nt][reg];
                unsigned u = __float_as_uint(v);
                ush h = (ush)(u >> 16);
                ush lo = f2bf(v - __uint_as_float(u & 0xFFFF0000u));
                oh[(rowb + reg) * 128 + col] = h;
                ol[(rowb + reg) * 128 + col] = lo;
            }
        }
}

// ---------------------------------------------------------------------------
// time path (xt bf16)
// ---------------------------------------------------------------------------
__global__ __launch_bounds__(256) void time_part1(const ush* __restrict__ xtb,
                                                  float* __restrict__ pP,
                                                  float* __restrict__ pQ) {
    int d = blockIdx.x * 256 + threadIdx.x;
    int r0 = blockIdx.y * 128;
    float sp = 0.f, sq = 0.f;
    for (int r = 0; r < 128; ++r) {
        float v = bf2f(xtb[(r0 + r) * 512 + d]);
        sp += v;
        sq += (float)(r0 + r) * v;
    }
    pP[blockIdx.y * 512 + d] = sp;
    pQ[blockIdx.y * 512 + d] = sq;
}

__global__ __launch_bounds__(512) void time_part2(float* __restrict__ pP,
                                                  float* __restrict__ pQ,
                                                  float* __restrict__ Ad,
                                                  float* __restrict__ Qt) {
    int d = threadIdx.x;
    float rp = 0.f, rq = 0.f;
    for (int c = 0; c < 64; ++c) {
        int idx = c * 512 + d;
        float p = pP[idx], qv = pQ[idx];
        pP[idx] = rp; pQ[idx] = rq;
        rp += p; rq += qv;
    }
    Ad[d] = rp; Qt[d] = rq;
}

__global__ __launch_bounds__(256) void time_part3(const ush* __restrict__ xtb,
                                                  const float* __restrict__ pP,
                                                  const float* __restrict__ pQ,
                                                  const float* __restrict__ Ad,
                                                  const float* __restrict__ Qt,
                                                  float* __restrict__ out) {
    int d = blockIdx.x * 256 + threadIdx.x;
    int r0 = blockIdx.y * 128;
    float P = pP[blockIdx.y * 512 + d];
    float Q = pQ[blockIdx.y * 512 + d];
    float A = Ad[d], Qtot = Qt[d];
    for (int r = 0; r < 128; ++r) {
        int i = r0 + r;
        float v = bf2f(xtb[i * 512 + d]);
        P += v;
        float fi = (float)i;
        Q += fi * v;
        float B = 2.f * fi * P - 2.f * Q + Qtot - fi * A;
        int Si = 67108864 - (i * (i + 1)) / 2 - ((8191 - i) * (8192 - i)) / 2;
        float T = (8192.f * A - B) / (float)Si;
        out[i * 512 + d] = 0.5f * T;
    }
}

// ---------------------------------------------------------------------------
// pass1: softmax stats, j-split x8. grid (8 jchunks, 256 iblocks).
// ---------------------------------------------------------------------------
__global__ __launch_bounds__(256) void pass1(const ush* __restrict__ qhg,
                                             const ush* __restrict__ qlg,
                                             const ush* __restrict__ khg,
                                             const ush* __restrict__ klg,
                                             float* __restrict__ pm,
                                             float* __restrict__ pl) {
    __shared__ __align__(16) ush Kh[32 * 128];
    __shared__ __align__(16) ush Kl[32 * 128];
    __shared__ float sm_[2][32], sl_[2][32];
    const int t = threadIdx.x;
    const int lane = t & 63, w = t >> 6;
    const int rt = w & 1, ct = w >> 1;
    const int i0 = blockIdx.y * 32;
    const int jbase = blockIdx.x * 1024;
    const int l15 = lane & 15, g = lane >> 4;

    bf16x8 Qh[4], Ql[4];
    {
        int qrow = i0 + rt * 16 + l15;
        #pragma unroll
        for (int kt = 0; kt < 4; ++kt) {
            Qh[kt] = *(const bf16x8*)&qhg[qrow * 128 + kt * 32 + g * 8];
            Ql[kt] = *(const bf16x8*)&qlg[qrow * 128 + kt * 32 + g * 8];
        }
    }
    float m_run[4] = {-INFINITY, -INFINITY, -INFINITY, -INFINITY};
    float l_run[4] = {0.f, 0.f, 0.f, 0.f};

    for (int jt = 0; jt < 32; ++jt) {
        int j0 = jbase + jt * 32;
        __syncthreads();
        #pragma unroll
        for (int u = 0; u < 2; ++u) {
            int s = u * 256 + t;
            int n = s >> 4, gl = (s & 15) ^ (n & 15);
            int src = (j0 + n) * 128 + gl * 8;
            *(uint4*)&Kh[s * 8] = *(const uint4*)&khg[src];
            *(uint4*)&Kl[s * 8] = *(const uint4*)&klg[src];
        }
        __syncthreads();

        bf16x8 kbh[4], kbl[4];
        {
            int n = ct * 16 + l15;
            #pragma unroll
            for (int kt = 0; kt < 4; ++kt) {
                int slot = n * 16 + ((kt * 4 + g) ^ (n & 15));
                kbh[kt] = *(const bf16x8*)&Kh[slot * 8];
                kbl[kt] = *(const bf16x8*)&Kl[slot * 8];
            }
        }
        f32x4 s4 = {0.f, 0.f, 0.f, 0.f};
        #pragma unroll
        for (int kt = 0; kt < 4; ++kt) s4 = __builtin_amdgcn_mfma_f32_16x16x32_bf16(Qh[kt], kbh[kt], s4, 0, 0, 0);
        #pragma unroll
        for (int kt = 0; kt < 4; ++kt) s4 = __builtin_amdgcn_mfma_f32_16x16x32_bf16(Ql[kt], kbh[kt], s4, 0, 0, 0);
        #pragma unroll
        for (int kt = 0; kt < 4; ++kt) s4 = __builtin_amdgcn_mfma_f32_16x16x32_bf16(Qh[kt], kbl[kt], s4, 0, 0, 0);

        #pragma unroll
        for (int reg = 0; reg < 4; ++reg) {
            float s = s4[reg];
            float mx = s;
            mx = fmaxf(mx, __shfl_xor(mx, 1));
            mx = fmaxf(mx, __shfl_xor(mx, 2));
            mx = fmaxf(mx, __shfl_xor(mx, 4));
            mx = fmaxf(mx, __shfl_xor(mx, 8));
            float mn = fmaxf(m_run[reg], mx);
            float p = __expf(s - mn);
            p += __shfl_xor(p, 1);
            p += __shfl_xor(p, 2);
            p += __shfl_xor(p, 4);
            p += __shfl_xor(p, 8);
            l_run[reg] = l_run[reg] * __expf(m_run[reg] - mn) + p;
            m_run[reg] = mn;
        }
    }
    if (l15 == 0) {
        #pragma unroll
        for (int reg = 0; reg < 4; ++reg) {
            sm_[ct][rt * 16 + g * 4 + reg] = m_run[reg];
            sl_[ct][rt * 16 + g * 4 + reg] = l_run[reg];
        }
    }
    __syncthreads();
    if (t < 32) {
        float M = fmaxf(sm_[0][t], sm_[1][t]);
        float l = sl_[0][t] * __expf(sm_[0][t] - M) + sl_[1][t] * __expf(sm_[1][t] - M);
        pm[blockIdx.x * 8192 + i0 + t] = M;
        pl[blockIdx.x * 8192 + i0 + t] = l;
    }
}

__global__ __launch_bounds__(256) void merge_stats(const float* __restrict__ pm,
                                                   const float* __restrict__ pl,
                                                   float* __restrict__ Mrow,
                                                   float* __restrict__ Rl) {
    int i = blockIdx.x * 256 + threadIdx.x;
    float M = pm[i];
    #pragma unroll
    for (int js = 1; js < 8; ++js) M = fmaxf(M, pm[js * 8192 + i]);
    float l = 0.f;
    #pragma unroll
    for (int js = 0; js < 8; ++js) l += pl[js * 8192 + i] * __expf(pm[js * 8192 + i] - M);
    Mrow[i] = M;
    Rl[i] = 1.0f / l;
}

// ---------------------------------------------------------------------------
// pass2: O_partial = exp(S-M)/l @ V, transposed PV, grid (2 jhalves, 128 strips)
// ---------------------------------------------------------------------------
__global__ __launch_bounds__(256, 1) void pass2(const ush* __restrict__ qhg,
                                                const ush* __restrict__ qlg,
                                                const ush* __restrict__ khg,
                                                const ush* __restrict__ klg,
                                                const ush* __restrict__ vtg,
                                                const float* __restrict__ Mrow,
                                                const float* __restrict__ Rl,
                                                ush* __restrict__ part0,
                                                ush* __restrict__ part1) {
    __shared__ __align__(16) ush Kh[32 * 128];
    __shared__ __align__(16) ush Kl[32 * 128];
    __shared__ __align__(16) ush Vt[512 * 32];
    __shared__ __align__(16) ush P[64 * 40];

    const int t = threadIdx.x;
    const int lane = t & 63, w = t >> 6;
    const int l15 = lane & 15, g = lane >> 4;
    const int i0 = blockIdx.y * 64;
    const int jbase = blockIdx.x * 4096;

    bf16x8 Qh[2][4], Ql[2][4];
    #pragma unroll
    for (int rt = 0; rt < 2; ++rt) {
        int qrow = i0 + 32 * (w & 1) + rt * 16 + l15;
        #pragma unroll
        for (int kt = 0; kt < 4; ++kt) {
            Qh[rt][kt] = *(const bf16x8*)&qhg[qrow * 128 + kt * 32 + g * 8];
            Ql[rt][kt] = *(const bf16x8*)&qlg[qrow * 128 + kt * 32 + g * 8];
        }
    }
    float Mv[2][4], Rv[2][4];
    #pragma unroll
    for (int rt = 0; rt < 2; ++rt)
        #pragma unroll
        for (int reg = 0; reg < 4; ++reg) {
            int row = i0 + 32 * (w & 1) + rt * 16 + g * 4 + reg;
            Mv[rt][reg] = Mrow[row];
            Rv[rt][reg] = Rl[row];
        }

    f32x4 acc[8][4];
    #pragma unroll
    for (int mt = 0; mt < 8; ++mt)
        #pragma unroll
        for (int nt = 0; nt < 4; ++nt)
            acc[mt][nt] = (f32x4){0.f, 0.f, 0.f, 0.f};

    for (int jt = 0; jt < 128; ++jt) {
        const int j0 = jbase + jt * 32;
        __syncthreads();
        #pragma unroll
        for (int u = 0; u < 2; ++u) {
            int s = u * 256 + t;
            int n = s >> 4, gl = (s & 15) ^ (n & 15);
            int src = (j0 + n) * 128 + gl * 8;
            *(uint4*)&Kh[s * 8] = *(const uint4*)&khg[src];
            *(uint4*)&Kl[s * 8] = *(const uint4*)&klg[src];
        }
        #pragma unroll
        for (int u = 0; u < 8; ++u) {
            int s = u * 256 + t;
            int c = s >> 2, gl = (s & 3) ^ ((c >> 1) & 3);
            *(uint4*)&Vt[s * 8] = *(const uint4*)&vtg[c * 8192 + j0 + gl * 8];
        }
        __syncthreads();

        bf16x8 kbh[4], kbl[4];
        {
            int n = (w >> 1) * 16 + l15;
            #pragma unroll
            for (int kt = 0; kt < 4; ++kt) {
                int slot = n * 16 + ((kt * 4 + g) ^ (n & 15));
                kbh[kt] = *(const bf16x8*)&Kh[slot * 8];
                kbl[kt] = *(const bf16x8*)&Kl[slot * 8];
            }
        }
        #pragma unroll
        for (int rt = 0; rt < 2; ++rt) {
            f32x4 s4 = {0.f, 0.f, 0.f, 0.f};
            #pragma unroll
            for (int kt = 0; kt < 4; ++kt) s4 = __builtin_amdgcn_mfma_f32_16x16x32_bf16(Qh[rt][kt], kbh[kt], s4, 0, 0, 0);
            #pragma unroll
            for (int kt = 0; kt < 4; ++kt) s4 = __builtin_amdgcn_mfma_f32_16x16x32_bf16(Ql[rt][kt], kbh[kt], s4, 0, 0, 0);
            #pragma unroll
            for (int kt = 0; kt < 4; ++kt) s4 = __builtin_amdgcn_mfma_f32_16x16x32_bf16(Qh[rt][kt], kbl[kt], s4, 0, 0, 0);
            #pragma unroll
            for (int reg = 0; reg < 4; ++reg) {
                float p = __expf(s4[reg] - Mv[rt][reg]) * Rv[rt][reg];
                int row = 32 * (w & 1) + rt * 16 + g * 4 + reg;
                int col = (w >> 1) * 16 + l15;
                P[row * 40 + col] = f2bf(p);
            }
        }
        __syncthreads();

        bf16x8 Pb[4];
        #pragma unroll
        for (int nt = 0; nt < 4; ++nt)
            Pb[nt] = *(const bf16x8*)&P[(nt * 16 + l15) * 40 + g * 8];
        #pragma unroll
        for (int mt = 0; mt < 8; ++mt) {
            int c = w * 128 + mt * 16 + l15;
            int slot = c * 4 + (g ^ ((c >> 1) & 3));
            bf16x8 vf = *(const bf16x8*)&Vt[slot * 8];
            #pragma unroll
            for (int nt = 0; nt < 4; ++nt)
                acc[mt][nt] = __builtin_amdgcn_mfma_f32_16x16x32_bf16(vf, Pb[nt], acc[mt][nt], 0, 0, 0);
        }
    }

    ush* prt = (blockIdx.x == 0) ? part0 : part1;
    #pragma unroll
    for (int mt = 0; mt < 8; ++mt)
        #pragma unroll
        for (int nt = 0; nt < 4; ++nt) {
            int qrow = i0 + nt * 16 + l15;
            int vcol = w * 128 + mt * 16 + g * 4;
            uint2 pk;
            pk.x = (unsigned)f2bf(acc[mt][nt][0]) | ((unsigned)f2bf(acc[mt][nt][1]) << 16);
            pk.y = (unsigned)f2bf(acc[mt][nt][2]) | ((unsigned)f2bf(acc[mt][nt][3]) << 16);
            *(uint2*)&prt[qrow * 512 + vcol] = pk;
        }
}

// ---------------------------------------------------------------------------
// merge_k — out += 0.5 * (part0 + part1)
// ---------------------------------------------------------------------------
__global__ __launch_bounds__(256) void merge_k(const ush* __restrict__ p0,
                                               const ush* __restrict__ p1,
                                               float* __restrict__ out) {
    int base = (blockIdx.x * 256 + threadIdx.x) * 8;
    uint4 a = *(const uint4*)&p0[base];
    uint4 b = *(const uint4*)&p1[base];
    float4 o0 = *(float4*)&out[base];
    float4 o1 = *(float4*)&out[base + 4];
    unsigned av[4] = {a.x, a.y, a.z, a.w};
    unsigned bv[4] = {b.x, b.y, b.z, b.w};
    float r[8];
    #pragma unroll
    for (int i = 0; i < 4; ++i) {
        r[2 * i + 0] = 0.5f * (bf2f((ush)(av[i] & 0xFFFF)) + bf2f((ush)(bv[i] & 0xFFFF)));
        r[2 * i + 1] = 0.5f * (bf2f((ush)(av[i] >> 16)) + bf2f((ush)(bv[i] >> 16)));
    }
    o0.x += r[0]; o0.y += r[1]; o0.z += r[2]; o0.w += r[3];
    o1.x += r[4]; o1.y += r[5]; o1.z += r[6]; o1.w += r[7];
    *(float4*)&out[base] = o0;
    *(float4*)&out[base + 4] = o1;
}

// ---------------------------------------------------------------------------
extern "C" void kernel_launch(void* const* d_in, const int* in_sizes, int n_in,
                              void* d_out, int out_size, void* d_ws, size_t ws_size,
                              hipStream_t stream) {
    const float* x  = (const float*)d_in[0];
    const float* W0 = (const float*)d_in[1];
    const float* W1 = (const float*)d_in[2];
    const float* wm = (const float*)d_in[3];
    const float* wt = (const float*)d_in[4];
    float* out = (float*)d_out;
    float* ws  = (float*)d_ws;

    // Region A
    ush* vtg = (ush*)(ws + 0);
    // Region B: xt bf16, then stats overlay after time path
    ush* xtb  = (ush*)(ws + 2097152);
    float* Mr = ws + 2097152;
    float* Rl = ws + 2105344;
    float* pm = ws + 2113536;
    float* pl = ws + 2179072;
    // Region C: weights (early) -> partials (late).  FIXED OFFSETS (R3 bug:
    // W01l overlapped W01h's second half — W01h/W01l each need 65536 floats).
    ush* W01h = (ush*)(ws + 4194304);
    ush* W01l = (ush*)(ws + 4259840);
    ush* wmTh = (ush*)(ws + 4325376);
    ush* wmTl = (ush*)(ws + 4456448);
    ush* wtTh = (ush*)(ws + 4587520);
    ush* wtTl = (ush*)(ws + 4718592);
    ush* part0 = (ush*)(ws + 4194304);
    ush* part1 = (ush*)(ws + 6291456);
    // Region D
    ush* qh = (ush*)(ws + 8388608);
    ush* ql = (ush*)(ws + 8912896);
    ush* kh = (ush*)(ws + 9437184);
    ush* kl = (ush*)(ws + 9961472);
    // Region E
    float* pP = ws + 10485760;
    float* pQ = ws + 10518528;
    float* Ad = ws + 10551296;
    float* Qt = ws + 10551808;

    cast_w01   <<<dim3(64),       256, 0, stream>>>(W0, W1, W01h, W01l);
    cast_wT    <<<dim3(8, 8, 2),  256, 0, stream>>>(wm, wt, wmTh, wmTl, wtTh, wtTl);
    gemm_xv    <<<dim3(4, 64, 2), 256, 0, stream>>>(x, wmTh, wmTl, wtTh, wtTl, vtg, xtb);
    gemm_qk    <<<dim3(2, 64),    256, 0, stream>>>(x, W01h, W01l, qh, ql, kh, kl);
    time_part1 <<<dim3(2, 64),    256, 0, stream>>>(xtb, pP, pQ);
    time_part2 <<<dim3(1),        512, 0, stream>>>(pP, pQ, Ad, Qt);
    time_part3 <<<dim3(2, 64),    256, 0, stream>>>(xtb, pP, pQ, Ad, Qt, out);
    pass1      <<<dim3(8, 256),   256, 0, stream>>>(qh, ql, kh, kl, pm, pl);
    merge_stats<<<dim3(32),       256, 0, stream>>>(pm, pl, Mr, Rl);
    pass2      <<<dim3(2, 128),   256, 0, stream>>>(qh, ql, kh, kl, vtg, Mr, Rl, part0, part1);
    merge_k    <<<dim3(2048),     256, 0, stream>>>(part0, part1, out);
}